// Round 16
// baseline (122.750 us; speedup 1.0000x reference)
//
#include <hip/hip_runtime.h>
#include <hip/hip_bf16.h>
#include <math.h>

#define N_ROWS 4096
#define D 512
#define TWO_N 8192
#define BM 256               /* tile edge */
#define NKT 4                /* 512 / 128 K-tiles */
#define NJB2 32              /* 8192 / 256 panels */
#define NPAIRS2 528          /* 32*33/2 upper-tri panel pairs */
#define INV_T 5.0f

typedef __attribute__((ext_vector_type(4))) int i32x4;
typedef __attribute__((ext_vector_type(8))) int i32x8;
typedef __attribute__((ext_vector_type(2))) float f32x2;
typedef __attribute__((ext_vector_type(4))) float f32x4;
#define AS1 __attribute__((address_space(1)))
#define AS3 __attribute__((address_space(3)))

// ---------------- block reduction helper (broadcasts result) ----------------
template<int K>
__device__ inline void block_reduce_bcast(float (&v)[K]) {
  __shared__ float red[4][K];
  const int t = threadIdx.x;
  #pragma unroll
  for (int off = 32; off; off >>= 1)
    #pragma unroll
    for (int i = 0; i < K; ++i) v[i] += __shfl_xor(v[i], off, 64);
  __syncthreads();
  if ((t & 63) == 0)
    #pragma unroll
    for (int i = 0; i < K; ++i) red[t >> 6][i] = v[i];
  __syncthreads();
  #pragma unroll
  for (int i = 0; i < K; ++i) v[i] = red[0][i] + red[1][i] + red[2][i] + red[3][i];
}

// ---------------- kernel 1: wave-per-row normalize -> fp8 e4m3 reps --------
__global__ __launch_bounds__(256) void normalize_kernel(
    const float* __restrict__ ei_, const float* __restrict__ ej_,
    const float* __restrict__ ek_,
    unsigned char* __restrict__ rep8, float* __restrict__ diagexp,
    float* __restrict__ pos_ij, float* __restrict__ exp_ik)
{
  const int t = threadIdx.x;
  const int l = t & 63;
  const int n = blockIdx.x * 4 + (t >> 6);
  const long base = (long)n * D + l * 8;

  float ai[8], aj[8], ak[8];
  #pragma unroll
  for (int h = 0; h < 2; ++h) {
    const float4 vi = *reinterpret_cast<const float4*>(ei_ + base + h * 4);
    const float4 vj = *reinterpret_cast<const float4*>(ej_ + base + h * 4);
    const float4 vk = *reinterpret_cast<const float4*>(ek_ + base + h * 4);
    ai[h*4+0]=vi.x; ai[h*4+1]=vi.y; ai[h*4+2]=vi.z; ai[h*4+3]=vi.w;
    aj[h*4+0]=vj.x; aj[h*4+1]=vj.y; aj[h*4+2]=vj.z; aj[h*4+3]=vj.w;
    ak[h*4+0]=vk.x; ak[h*4+1]=vk.y; ak[h*4+2]=vk.z; ak[h*4+3]=vk.w;
  }

  float v[5] = {0.f, 0.f, 0.f, 0.f, 0.f};
  #pragma unroll
  for (int j = 0; j < 8; ++j) {
    v[0] += ai[j] * ai[j];
    v[1] += aj[j] * aj[j];
    v[2] += ak[j] * ak[j];
    v[3] += ai[j] * aj[j];
    v[4] += ak[j] * ai[j];
  }
  #pragma unroll
  for (int off = 32; off; off >>= 1)
    #pragma unroll
    for (int i = 0; i < 5; ++i) v[i] += __shfl_xor(v[i], off, 64);

  const float ni = fmaxf(sqrtf(v[0]), 1e-12f);
  const float nj = fmaxf(sqrtf(v[1]), 1e-12f);
  const float nk = fmaxf(sqrtf(v[2]), 1e-12f);
  const float invi = 1.0f / ni, invj = 1.0f / nj;

  float zi[8], zj[8];
  #pragma unroll
  for (int j = 0; j < 8; ++j) { zi[j] = ai[j] * invi; zj[j] = aj[j] * invj; }
  int wi0 = __builtin_amdgcn_cvt_pk_fp8_f32(zi[0], zi[1], 0, false);
  wi0     = __builtin_amdgcn_cvt_pk_fp8_f32(zi[2], zi[3], wi0, true);
  int wi1 = __builtin_amdgcn_cvt_pk_fp8_f32(zi[4], zi[5], 0, false);
  wi1     = __builtin_amdgcn_cvt_pk_fp8_f32(zi[6], zi[7], wi1, true);
  int wj0 = __builtin_amdgcn_cvt_pk_fp8_f32(zj[0], zj[1], 0, false);
  wj0     = __builtin_amdgcn_cvt_pk_fp8_f32(zj[2], zj[3], wj0, true);
  int wj1 = __builtin_amdgcn_cvt_pk_fp8_f32(zj[4], zj[5], 0, false);
  wj1     = __builtin_amdgcn_cvt_pk_fp8_f32(zj[6], zj[7], wj1, true);
  int2 pi; pi.x = wi0; pi.y = wi1;
  int2 pj; pj.x = wj0; pj.y = wj1;
  *reinterpret_cast<int2*>(rep8 + base) = pi;
  *reinterpret_cast<int2*>(rep8 + (long)N_ROWS * D + base) = pj;

  // diag = sum of squares of the DEQUANTIZED values (matches MFMA diagonal)
  float q[2] = {0.f, 0.f};
  #pragma unroll
  for (int h = 0; h < 2; ++h) {
    const int wi = h ? wi1 : wi0, wj = h ? wj1 : wj0;
    const f32x2 d0 = __builtin_amdgcn_cvt_pk_f32_fp8(wi, false);
    const f32x2 d1 = __builtin_amdgcn_cvt_pk_f32_fp8(wi, true);
    const f32x2 e0 = __builtin_amdgcn_cvt_pk_f32_fp8(wj, false);
    const f32x2 e1 = __builtin_amdgcn_cvt_pk_f32_fp8(wj, true);
    q[0] += d0.x*d0.x + d0.y*d0.y + d1.x*d1.x + d1.y*d1.y;
    q[1] += e0.x*e0.x + e0.y*e0.y + e1.x*e1.x + e1.y*e1.y;
  }
  #pragma unroll
  for (int off = 32; off; off >>= 1)
    #pragma unroll
    for (int i = 0; i < 2; ++i) q[i] += __shfl_xor(q[i], off, 64);

  if (l == 0) {
    diagexp[n]          = __expf(INV_T * q[0]);
    diagexp[N_ROWS + n] = __expf(INV_T * q[1]);
    pos_ij[n] = v[3] / (ni * nj);
    exp_ik[n] = __expf(INV_T * v[4] / (nk * ni));
  }
}

// ---------------- kernel 2: reduce the two scalars --------------------------
__global__ __launch_bounds__(256) void scalar_kernel(
    const float* __restrict__ pos_ij, const float* __restrict__ exp_ik,
    float* __restrict__ scalars)
{
  const int t = threadIdx.x;
  float v[2] = {0.f, 0.f};
  for (int i = t; i < N_ROWS; i += 256) { v[0] += pos_ij[i]; v[1] += exp_ik[i]; }
  block_reduce_bcast<2>(v);
  if (t == 0) { scalars[0] = v[0]; scalars[1] = v[1]; }
}

// ---------------- kernel 3: 256^2 MX-fp8 K=128 GEMM + exp + sums -----------
// 4x FLOP per block vs 128^2: per barrier interval a wave runs 32 mfma_scale
// (~1100 cyc) against the same stage+drain -> ~2x busy fraction; staging
// traffic per CU halves; barrier count per CU drops 4x. 512 threads, 8 waves
// (wm2 x wn4: per-wave 128x64 out, acc[8][4] = 128 VGPR, est ~215 total).
// __launch_bounds__(512) only (cap 256; R10/R14: never set min-waves).
// LDS 64KB single buffer [A 256x128B | B 256x128B]; 2 barriers/K-tile.
// Row = 128B = 8 slots of 16B; swizzle slot^(row&7); inverse on source.
__device__ __forceinline__ void stage256(
    const unsigned char* __restrict__ rep8, char* region,
    long R0, int kt, int t)
{
  #pragma unroll
  for (int s = 0; s < 4; ++s) {
    const int cc = s * 512 + t;          // chunk 0..2047
    const int row = cc >> 3, slot = cc & 7;
    const int sg = slot ^ (row & 7);     // inverse-swizzled source slot
    const unsigned char* g = rep8 + (R0 + row) * D + kt * 128 + sg * 16;
    __builtin_amdgcn_global_load_lds((const AS1 void*)g,
        (AS3 void*)(region + cc * 16), 16, 0, 0);
  }
}

__global__ __launch_bounds__(512) void gemm_expsum_kernel(
    const unsigned char* __restrict__ rep8, float* __restrict__ S_partial)
{
  __shared__ __align__(16) char smem[65536];   // A 32K | B 32K

  const int t = threadIdx.x;
  const int l = t & 63;
  const int w = t >> 6;          // wave 0..7
  const int wm = w >> 2;         // row half 0..1 (128 rows)
  const int wn = w & 3;          // col quarter 0..3 (64 cols)
  const int s4 = l >> 4;         // k-group 0..3

  // XCD-aware bijective swizzle (528 = 8*66), then triangular decode I<=J
  const int wg = (blockIdx.x & 7) * 66 + (blockIdx.x >> 3);
  int k = wg, I = 0;
  while (k >= NJB2 - I) { k -= NJB2 - I; ++I; }
  const int J = I + k;
  const long rI = (long)I * BM;
  const long cJ = (long)J * BM;

  // fragment byte offsets: row*128 + ((2g+h)^(row&7))*16
  int a_off[8][2], b_off[4][2];
  #pragma unroll
  for (int mi = 0; mi < 8; ++mi) {
    const int r = wm * 128 + mi * 16 + (l & 15);
    #pragma unroll
    for (int h = 0; h < 2; ++h)
      a_off[mi][h] = r * 128 + (((s4 * 2 + h) ^ (r & 7)) * 16);
  }
  #pragma unroll
  for (int ni = 0; ni < 4; ++ni) {
    const int r = wn * 64 + ni * 16 + (l & 15);
    #pragma unroll
    for (int h = 0; h < 2; ++h)
      b_off[ni][h] = 32768 + r * 128 + (((s4 * 2 + h) ^ (r & 7)) * 16);
  }

  f32x4 acc[8][4];
  #pragma unroll
  for (int a = 0; a < 8; ++a)
    #pragma unroll
    for (int b = 0; b < 4; ++b) { f32x4 z = {0.f, 0.f, 0.f, 0.f}; acc[a][b] = z; }

  for (int kt = 0; kt < NKT; ++kt) {
    if (kt) __syncthreads();             // everyone done reading prev tile
    stage256(rep8, smem, rI, kt, t);
    stage256(rep8, smem + 32768, cJ, kt, t);
    __syncthreads();                     // drains vmcnt(0): tile landed

    i32x8 bf[4];
    #pragma unroll
    for (int ni = 0; ni < 4; ++ni) {
      const i32x4 lo = *reinterpret_cast<const i32x4*>(smem + b_off[ni][0]);
      const i32x4 hi = *reinterpret_cast<const i32x4*>(smem + b_off[ni][1]);
      bf[ni] = __builtin_shufflevector(lo, hi, 0, 1, 2, 3, 4, 5, 6, 7);
    }
    __builtin_amdgcn_s_setprio(1);
    #pragma unroll
    for (int mi = 0; mi < 8; ++mi) {
      const i32x4 lo = *reinterpret_cast<const i32x4*>(smem + a_off[mi][0]);
      const i32x4 hi = *reinterpret_cast<const i32x4*>(smem + a_off[mi][1]);
      const i32x8 af = __builtin_shufflevector(lo, hi, 0, 1, 2, 3, 4, 5, 6, 7);
      #pragma unroll
      for (int ni = 0; ni < 4; ++ni)
        acc[mi][ni] = __builtin_amdgcn_mfma_scale_f32_16x16x128_f8f6f4(
            af, bf[ni], acc[mi][ni], 0 /*A fmt fp8*/, 0 /*B fmt fp8*/,
            0, 0x7F7F7F7F, 0, 0x7F7F7F7F);
    }
    __builtin_amdgcn_s_setprio(0);
  }
  __syncthreads();                       // all ds_reads retired: smem reusable
  float* rowbuf = (float*)smem;          // [4 wn][256]
  float* colbuf = (float*)(smem + 4096); // [2 wm][256]

  // epilogue: e = exp(5*sim); row-sums (rows of I) and col-sums (symmetry)
  // C/D layout shape-determined: col=l&15, row=(l>>4)*4+j  (R3/R4-verified
  // 256^2 epilogue structure)
  float rsum[8][4], csum[4];
  #pragma unroll
  for (int mi = 0; mi < 8; ++mi)
    #pragma unroll
    for (int j = 0; j < 4; ++j) rsum[mi][j] = 0.f;
  #pragma unroll
  for (int ni = 0; ni < 4; ++ni) csum[ni] = 0.f;

  #pragma unroll
  for (int mi = 0; mi < 8; ++mi)
    #pragma unroll
    for (int ni = 0; ni < 4; ++ni)
      #pragma unroll
      for (int j = 0; j < 4; ++j) {
        const float e = __expf(INV_T * acc[mi][ni][j]);
        rsum[mi][j] += e;
        csum[ni]   += e;
      }

  #pragma unroll
  for (int mi = 0; mi < 8; ++mi) {
    #pragma unroll
    for (int off = 1; off < 16; off <<= 1)
      #pragma unroll
      for (int j = 0; j < 4; ++j) rsum[mi][j] += __shfl_xor(rsum[mi][j], off, 64);
    if ((l & 15) == 0) {
      const int rloc = wm * 128 + mi * 16 + s4 * 4;
      #pragma unroll
      for (int j = 0; j < 4; ++j) rowbuf[wn * BM + rloc + j] = rsum[mi][j];
    }
  }
  #pragma unroll
  for (int off = 16; off < 64; off <<= 1)
    #pragma unroll
    for (int ni = 0; ni < 4; ++ni) csum[ni] += __shfl_xor(csum[ni], off, 64);
  if (l < 16) {
    #pragma unroll
    for (int ni = 0; ni < 4; ++ni)
      colbuf[wm * BM + wn * 64 + ni * 16 + l] = csum[ni];
  }
  __syncthreads();

  if (t < BM) {
    S_partial[(long)J * TWO_N + rI + t] =
        rowbuf[t] + rowbuf[BM + t] + rowbuf[2 * BM + t] + rowbuf[3 * BM + t];
  } else if (I != J) {
    const int c = t - BM;
    S_partial[(long)I * TWO_N + cJ + c] = colbuf[c] + colbuf[BM + c];
  }
}

// ---------------- kernel 4: per-row log(denominator), block partials -------
__global__ __launch_bounds__(256) void rowlog_kernel(
    const float* __restrict__ S_partial, const float* __restrict__ diagexp,
    const float* __restrict__ scalars, float* __restrict__ blockpart)
{
  const int t = threadIdx.x;
  const int r = blockIdx.x * 256 + t;
  float s = 0.f;
  #pragma unroll 8
  for (int Jb = 0; Jb < NJB2; ++Jb) s += S_partial[(long)Jb * TWO_N + r];
  const float denom_fu = 2.0f * scalars[1];
  float v[1];
  v[0] = logf(s - diagexp[r] + denom_fu);
  block_reduce_bcast<1>(v);
  if (t == 0) blockpart[blockIdx.x] = v[0];
}

// ---------------- kernel 5: final scalar -----------------------------------
__global__ void final_kernel(const float* __restrict__ blockpart,
                             const float* __restrict__ scalars,
                             float* __restrict__ out)
{
  const int t = threadIdx.x;   // 64 threads
  float s = (t < TWO_N / 256) ? blockpart[t] : 0.f;
  #pragma unroll
  for (int off = 32; off; off >>= 1) s += __shfl_xor(s, off, 64);
  if (t == 0) out[0] = (s - 10.0f * scalars[0]) / (float)TWO_N;
}

extern "C" void kernel_launch(void* const* d_in, const int* in_sizes, int n_in,
                              void* d_out, int out_size, void* d_ws, size_t ws_size,
                              hipStream_t stream)
{
  const float* ei = (const float*)d_in[0];
  const float* ej = (const float*)d_in[1];
  const float* ek = (const float*)d_in[2];
  float* out = (float*)d_out;

  char* ws = (char*)d_ws;
  unsigned char* rep8 = (unsigned char*)ws;                            // 4 MB
  float* S_partial = (float*)(ws + 4u * 1024 * 1024);                  // 1 MB
  float* diagexp   = (float*)(ws + 6u * 1024 * 1024);                  // 32 KB
  float* pos_ij    = (float*)(ws + 6u * 1024 * 1024 + 32 * 1024);      // 16 KB
  float* exp_ik    = (float*)(ws + 6u * 1024 * 1024 + 48 * 1024);      // 16 KB
  float* scalars   = (float*)(ws + 6u * 1024 * 1024 + 64 * 1024);      // 8 B
  float* blockpart = (float*)(ws + 6u * 1024 * 1024 + 64 * 1024 + 256); // 128 B

  normalize_kernel<<<N_ROWS / 4, 256, 0, stream>>>(ei, ej, ek, rep8, diagexp,
                                                   pos_ij, exp_ik);
  scalar_kernel<<<1, 256, 0, stream>>>(pos_ij, exp_ik, scalars);
  gemm_expsum_kernel<<<NPAIRS2, 512, 0, stream>>>(rep8, S_partial);
  rowlog_kernel<<<TWO_N / 256, 256, 0, stream>>>(S_partial, diagexp, scalars,
                                                 blockpart);
  final_kernel<<<1, 64, 0, stream>>>(blockpart, scalars, out);
}

// Round 17
// 121.642 us; speedup vs baseline: 1.0091x; 1.0091x over previous
//
#include <hip/hip_runtime.h>
#include <hip/hip_bf16.h>
#include <math.h>

#define N_ROWS 4096
#define D 512
#define TWO_N 8192
#define BM 256               /* tile edge */
#define NKT 4                /* 512 / 128 K-tiles */
#define NJB2 32              /* 8192 / 256 panels */
#define NPAIRS2 528          /* 32*33/2 upper-tri panel pairs */
#define INV_T 5.0f

typedef __attribute__((ext_vector_type(4))) int i32x4;
typedef __attribute__((ext_vector_type(8))) int i32x8;
typedef __attribute__((ext_vector_type(2))) float f32x2;
typedef __attribute__((ext_vector_type(4))) float f32x4;
#define AS1 __attribute__((address_space(1)))
#define AS3 __attribute__((address_space(3)))

// ---------------- block reduction helper (broadcasts result) ----------------
template<int K>
__device__ inline void block_reduce_bcast(float (&v)[K]) {
  __shared__ float red[4][K];
  const int t = threadIdx.x;
  #pragma unroll
  for (int off = 32; off; off >>= 1)
    #pragma unroll
    for (int i = 0; i < K; ++i) v[i] += __shfl_xor(v[i], off, 64);
  __syncthreads();
  if ((t & 63) == 0)
    #pragma unroll
    for (int i = 0; i < K; ++i) red[t >> 6][i] = v[i];
  __syncthreads();
  #pragma unroll
  for (int i = 0; i < K; ++i) v[i] = red[0][i] + red[1][i] + red[2][i] + red[3][i];
}

// ---------------- kernel 1: wave-per-row normalize -> fp8 e4m3 reps --------
__global__ __launch_bounds__(256) void normalize_kernel(
    const float* __restrict__ ei_, const float* __restrict__ ej_,
    const float* __restrict__ ek_,
    unsigned char* __restrict__ rep8, float* __restrict__ diagexp,
    float* __restrict__ pos_ij, float* __restrict__ exp_ik)
{
  const int t = threadIdx.x;
  const int l = t & 63;
  const int n = blockIdx.x * 4 + (t >> 6);
  const long base = (long)n * D + l * 8;

  float ai[8], aj[8], ak[8];
  #pragma unroll
  for (int h = 0; h < 2; ++h) {
    const float4 vi = *reinterpret_cast<const float4*>(ei_ + base + h * 4);
    const float4 vj = *reinterpret_cast<const float4*>(ej_ + base + h * 4);
    const float4 vk = *reinterpret_cast<const float4*>(ek_ + base + h * 4);
    ai[h*4+0]=vi.x; ai[h*4+1]=vi.y; ai[h*4+2]=vi.z; ai[h*4+3]=vi.w;
    aj[h*4+0]=vj.x; aj[h*4+1]=vj.y; aj[h*4+2]=vj.z; aj[h*4+3]=vj.w;
    ak[h*4+0]=vk.x; ak[h*4+1]=vk.y; ak[h*4+2]=vk.z; ak[h*4+3]=vk.w;
  }

  float v[5] = {0.f, 0.f, 0.f, 0.f, 0.f};
  #pragma unroll
  for (int j = 0; j < 8; ++j) {
    v[0] += ai[j] * ai[j];
    v[1] += aj[j] * aj[j];
    v[2] += ak[j] * ak[j];
    v[3] += ai[j] * aj[j];
    v[4] += ak[j] * ai[j];
  }
  #pragma unroll
  for (int off = 32; off; off >>= 1)
    #pragma unroll
    for (int i = 0; i < 5; ++i) v[i] += __shfl_xor(v[i], off, 64);

  const float ni = fmaxf(sqrtf(v[0]), 1e-12f);
  const float nj = fmaxf(sqrtf(v[1]), 1e-12f);
  const float nk = fmaxf(sqrtf(v[2]), 1e-12f);
  const float invi = 1.0f / ni, invj = 1.0f / nj;

  float zi[8], zj[8];
  #pragma unroll
  for (int j = 0; j < 8; ++j) { zi[j] = ai[j] * invi; zj[j] = aj[j] * invj; }
  int wi0 = __builtin_amdgcn_cvt_pk_fp8_f32(zi[0], zi[1], 0, false);
  wi0     = __builtin_amdgcn_cvt_pk_fp8_f32(zi[2], zi[3], wi0, true);
  int wi1 = __builtin_amdgcn_cvt_pk_fp8_f32(zi[4], zi[5], 0, false);
  wi1     = __builtin_amdgcn_cvt_pk_fp8_f32(zi[6], zi[7], wi1, true);
  int wj0 = __builtin_amdgcn_cvt_pk_fp8_f32(zj[0], zj[1], 0, false);
  wj0     = __builtin_amdgcn_cvt_pk_fp8_f32(zj[2], zj[3], wj0, true);
  int wj1 = __builtin_amdgcn_cvt_pk_fp8_f32(zj[4], zj[5], 0, false);
  wj1     = __builtin_amdgcn_cvt_pk_fp8_f32(zj[6], zj[7], wj1, true);
  int2 pi; pi.x = wi0; pi.y = wi1;
  int2 pj; pj.x = wj0; pj.y = wj1;
  *reinterpret_cast<int2*>(rep8 + base) = pi;
  *reinterpret_cast<int2*>(rep8 + (long)N_ROWS * D + base) = pj;

  // diag = sum of squares of the DEQUANTIZED values (matches MFMA diagonal)
  float q[2] = {0.f, 0.f};
  #pragma unroll
  for (int h = 0; h < 2; ++h) {
    const int wi = h ? wi1 : wi0, wj = h ? wj1 : wj0;
    const f32x2 d0 = __builtin_amdgcn_cvt_pk_f32_fp8(wi, false);
    const f32x2 d1 = __builtin_amdgcn_cvt_pk_f32_fp8(wi, true);
    const f32x2 e0 = __builtin_amdgcn_cvt_pk_f32_fp8(wj, false);
    const f32x2 e1 = __builtin_amdgcn_cvt_pk_f32_fp8(wj, true);
    q[0] += d0.x*d0.x + d0.y*d0.y + d1.x*d1.x + d1.y*d1.y;
    q[1] += e0.x*e0.x + e0.y*e0.y + e1.x*e1.x + e1.y*e1.y;
  }
  #pragma unroll
  for (int off = 32; off; off >>= 1)
    #pragma unroll
    for (int i = 0; i < 2; ++i) q[i] += __shfl_xor(q[i], off, 64);

  if (l == 0) {
    diagexp[n]          = __expf(INV_T * q[0]);
    diagexp[N_ROWS + n] = __expf(INV_T * q[1]);
    pos_ij[n] = v[3] / (ni * nj);
    exp_ik[n] = __expf(INV_T * v[4] / (nk * ni));
  }
}

// ---------------- kernel 2: reduce the two scalars --------------------------
__global__ __launch_bounds__(256) void scalar_kernel(
    const float* __restrict__ pos_ij, const float* __restrict__ exp_ik,
    float* __restrict__ scalars)
{
  const int t = threadIdx.x;
  float v[2] = {0.f, 0.f};
  for (int i = t; i < N_ROWS; i += 256) { v[0] += pos_ij[i]; v[1] += exp_ik[i]; }
  block_reduce_bcast<2>(v);
  if (t == 0) { scalars[0] = v[0]; scalars[1] = v[1]; }
}

// ---------------- kernel 3: 256^2 MX-fp8 K=128, dbuf stage-ahead -----------
// Compute-dominated regime: per K-tile matrix work ~2200cyc vs ~1200 staging.
// __launch_bounds__(512,2): VGPR cap 256 >= need ~215 (19% headroom). R16's
// bare (512) let the heuristic cap at 128 -> 179MB spill. R10/R14: tight caps
// thrash. 8 waves wm2 x wn4, per-wave 128x64, acc[8][4]=128 VGPR.
// LDS 128KB dynamic: 2 x [A 32K | B 32K]; R8 stage-ahead: stage(k+1) into
// p^1 BEFORE compute(k); one syncthreads/K-tile (drain hides under MFMA).
// Row = 128B = 8 slots of 16B; swizzle slot^(row&7); inverse on source.
__device__ __forceinline__ void stage256(
    const unsigned char* __restrict__ rep8, char* region,
    long R0, int kt, int t)
{
  #pragma unroll
  for (int s = 0; s < 4; ++s) {
    const int cc = s * 512 + t;          // chunk 0..2047
    const int row = cc >> 3, slot = cc & 7;
    const int sg = slot ^ (row & 7);     // inverse-swizzled source slot
    const unsigned char* g = rep8 + (R0 + row) * D + kt * 128 + sg * 16;
    __builtin_amdgcn_global_load_lds((const AS1 void*)g,
        (AS3 void*)(region + cc * 16), 16, 0, 0);
  }
}

__global__ __launch_bounds__(512, 2) void gemm_expsum_kernel(
    const unsigned char* __restrict__ rep8, float* __restrict__ S_partial)
{
  extern __shared__ __align__(16) char smem[];   // 131072: [p][A 32K | B 32K]

  const int t = threadIdx.x;
  const int l = t & 63;
  const int w = t >> 6;          // wave 0..7
  const int wm = w >> 2;         // row half 0..1 (128 rows)
  const int wn = w & 3;          // col quarter 0..3 (64 cols)
  const int s4 = l >> 4;         // k-group 0..3

  // XCD-aware bijective swizzle (528 = 8*66), then triangular decode I<=J
  const int wg = (blockIdx.x & 7) * 66 + (blockIdx.x >> 3);
  int k = wg, I = 0;
  while (k >= NJB2 - I) { k -= NJB2 - I; ++I; }
  const int J = I + k;
  const long rI = (long)I * BM;
  const long cJ = (long)J * BM;

  // fragment byte offsets within a buffer: row*128 + ((2g+h)^(row&7))*16
  int a_off[8][2], b_off[4][2];
  #pragma unroll
  for (int mi = 0; mi < 8; ++mi) {
    const int r = wm * 128 + mi * 16 + (l & 15);
    #pragma unroll
    for (int h = 0; h < 2; ++h)
      a_off[mi][h] = r * 128 + (((s4 * 2 + h) ^ (r & 7)) * 16);
  }
  #pragma unroll
  for (int ni = 0; ni < 4; ++ni) {
    const int r = wn * 64 + ni * 16 + (l & 15);
    #pragma unroll
    for (int h = 0; h < 2; ++h)
      b_off[ni][h] = 32768 + r * 128 + (((s4 * 2 + h) ^ (r & 7)) * 16);
  }

  f32x4 acc[8][4];
  #pragma unroll
  for (int a = 0; a < 8; ++a)
    #pragma unroll
    for (int b = 0; b < 4; ++b) { f32x4 z = {0.f, 0.f, 0.f, 0.f}; acc[a][b] = z; }

  // prologue: stage T0 into buf0; syncthreads drains vmcnt
  stage256(rep8, smem, rI, 0, t);
  stage256(rep8, smem + 32768, cJ, 0, t);
  __syncthreads();

  for (int kt = 0; kt < NKT; ++kt) {
    const int p = kt & 1;
    char* cur = smem + p * 65536;
    if (kt < NKT - 1) {                  // issue next tile BEFORE compute
      char* nxt = smem + (p ^ 1) * 65536;
      stage256(rep8, nxt, rI, kt + 1, t);
      stage256(rep8, nxt + 32768, cJ, kt + 1, t);
    }
    i32x8 bf[4];
    #pragma unroll
    for (int ni = 0; ni < 4; ++ni) {
      const i32x4 lo = *reinterpret_cast<const i32x4*>(cur + b_off[ni][0]);
      const i32x4 hi = *reinterpret_cast<const i32x4*>(cur + b_off[ni][1]);
      bf[ni] = __builtin_shufflevector(lo, hi, 0, 1, 2, 3, 4, 5, 6, 7);
    }
    __builtin_amdgcn_s_setprio(1);
    #pragma unroll
    for (int mi = 0; mi < 8; ++mi) {
      const i32x4 lo = *reinterpret_cast<const i32x4*>(cur + a_off[mi][0]);
      const i32x4 hi = *reinterpret_cast<const i32x4*>(cur + a_off[mi][1]);
      const i32x8 af = __builtin_shufflevector(lo, hi, 0, 1, 2, 3, 4, 5, 6, 7);
      #pragma unroll
      for (int ni = 0; ni < 4; ++ni)
        acc[mi][ni] = __builtin_amdgcn_mfma_scale_f32_16x16x128_f8f6f4(
            af, bf[ni], acc[mi][ni], 0 /*A fmt fp8*/, 0 /*B fmt fp8*/,
            0, 0x7F7F7F7F, 0, 0x7F7F7F7F);
    }
    __builtin_amdgcn_s_setprio(0);
    __syncthreads();   // drains vmcnt(0): T(k+1) landed; all reads of p done
  }
  float* rowbuf = (float*)smem;          // [4 wn][256] (smem dead now)
  float* colbuf = (float*)(smem + 4096); // [2 wm][256]

  // epilogue: e = exp(5*sim); row-sums (rows of I) and col-sums (symmetry)
  // C/D layout shape-determined: col=l&15, row=(l>>4)*4+j
  float rsum[8][4], csum[4];
  #pragma unroll
  for (int mi = 0; mi < 8; ++mi)
    #pragma unroll
    for (int j = 0; j < 4; ++j) rsum[mi][j] = 0.f;
  #pragma unroll
  for (int ni = 0; ni < 4; ++ni) csum[ni] = 0.f;

  #pragma unroll
  for (int mi = 0; mi < 8; ++mi)
    #pragma unroll
    for (int ni = 0; ni < 4; ++ni)
      #pragma unroll
      for (int j = 0; j < 4; ++j) {
        const float e = __expf(INV_T * acc[mi][ni][j]);
        rsum[mi][j] += e;
        csum[ni]   += e;
      }

  #pragma unroll
  for (int mi = 0; mi < 8; ++mi) {
    #pragma unroll
    for (int off = 1; off < 16; off <<= 1)
      #pragma unroll
      for (int j = 0; j < 4; ++j) rsum[mi][j] += __shfl_xor(rsum[mi][j], off, 64);
    if ((l & 15) == 0) {
      const int rloc = wm * 128 + mi * 16 + s4 * 4;
      #pragma unroll
      for (int j = 0; j < 4; ++j) rowbuf[wn * BM + rloc + j] = rsum[mi][j];
    }
  }
  #pragma unroll
  for (int off = 16; off < 64; off <<= 1)
    #pragma unroll
    for (int ni = 0; ni < 4; ++ni) csum[ni] += __shfl_xor(csum[ni], off, 64);
  if (l < 16) {
    #pragma unroll
    for (int ni = 0; ni < 4; ++ni)
      colbuf[wm * BM + wn * 64 + ni * 16 + l] = csum[ni];
  }
  __syncthreads();

  if (t < BM) {
    S_partial[(long)J * TWO_N + rI + t] =
        rowbuf[t] + rowbuf[BM + t] + rowbuf[2 * BM + t] + rowbuf[3 * BM + t];
  } else if (I != J) {
    const int c = t - BM;
    S_partial[(long)I * TWO_N + cJ + c] = colbuf[c] + colbuf[BM + c];
  }
}

// ---------------- kernel 4: per-row log(denominator), block partials -------
__global__ __launch_bounds__(256) void rowlog_kernel(
    const float* __restrict__ S_partial, const float* __restrict__ diagexp,
    const float* __restrict__ scalars, float* __restrict__ blockpart)
{
  const int t = threadIdx.x;
  const int r = blockIdx.x * 256 + t;
  float s = 0.f;
  #pragma unroll 8
  for (int Jb = 0; Jb < NJB2; ++Jb) s += S_partial[(long)Jb * TWO_N + r];
  const float denom_fu = 2.0f * scalars[1];
  float v[1];
  v[0] = logf(s - diagexp[r] + denom_fu);
  block_reduce_bcast<1>(v);
  if (t == 0) blockpart[blockIdx.x] = v[0];
}

// ---------------- kernel 5: final scalar -----------------------------------
__global__ void final_kernel(const float* __restrict__ blockpart,
                             const float* __restrict__ scalars,
                             float* __restrict__ out)
{
  const int t = threadIdx.x;   // 64 threads
  float s = (t < TWO_N / 256) ? blockpart[t] : 0.f;
  #pragma unroll
  for (int off = 32; off; off >>= 1) s += __shfl_xor(s, off, 64);
  if (t == 0) out[0] = (s - 10.0f * scalars[0]) / (float)TWO_N;
}

extern "C" void kernel_launch(void* const* d_in, const int* in_sizes, int n_in,
                              void* d_out, int out_size, void* d_ws, size_t ws_size,
                              hipStream_t stream)
{
  const float* ei = (const float*)d_in[0];
  const float* ej = (const float*)d_in[1];
  const float* ek = (const float*)d_in[2];
  float* out = (float*)d_out;

  char* ws = (char*)d_ws;
  unsigned char* rep8 = (unsigned char*)ws;                            // 4 MB
  float* S_partial = (float*)(ws + 4u * 1024 * 1024);                  // 1 MB
  float* diagexp   = (float*)(ws + 6u * 1024 * 1024);                  // 32 KB
  float* pos_ij    = (float*)(ws + 6u * 1024 * 1024 + 32 * 1024);      // 16 KB
  float* exp_ik    = (float*)(ws + 6u * 1024 * 1024 + 48 * 1024);      // 16 KB
  float* scalars   = (float*)(ws + 6u * 1024 * 1024 + 64 * 1024);      // 8 B
  float* blockpart = (float*)(ws + 6u * 1024 * 1024 + 64 * 1024 + 256); // 128 B

  static const int kSmemBytes = 131072;
  (void)hipFuncSetAttribute((const void*)gemm_expsum_kernel,
                            hipFuncAttributeMaxDynamicSharedMemorySize,
                            kSmemBytes);

  normalize_kernel<<<N_ROWS / 4, 256, 0, stream>>>(ei, ej, ek, rep8, diagexp,
                                                   pos_ij, exp_ik);
  scalar_kernel<<<1, 256, 0, stream>>>(pos_ij, exp_ik, scalars);
  gemm_expsum_kernel<<<NPAIRS2, 512, kSmemBytes, stream>>>(rep8, S_partial);
  rowlog_kernel<<<TWO_N / 256, 256, 0, stream>>>(S_partial, diagexp, scalars,
                                                 blockpart);
  final_kernel<<<1, 64, 0, stream>>>(blockpart, scalars, out);
}

// Round 18
// 90.926 us; speedup vs baseline: 1.3500x; 1.3378x over previous
//
#include <hip/hip_runtime.h>
#include <hip/hip_bf16.h>
#include <math.h>

#define N_ROWS 4096
#define D 512
#define TWO_N 8192
#define TILE 128
#define NKT 4                /* 512 / 128 K-tiles */
#define NJB 64               /* 8192 / 128 column blocks */
#define NPAIRS 2080          /* 64*65/2 upper-tri blocks */
#define INV_T 5.0f

typedef __attribute__((ext_vector_type(4))) int i32x4;
typedef __attribute__((ext_vector_type(8))) int i32x8;
typedef __attribute__((ext_vector_type(2))) float f32x2;
typedef __attribute__((ext_vector_type(4))) float f32x4;

// ---------------- block reduction helper (broadcasts result) ----------------
template<int K>
__device__ inline void block_reduce_bcast(float (&v)[K]) {
  __shared__ float red[4][K];
  const int t = threadIdx.x;
  #pragma unroll
  for (int off = 32; off; off >>= 1)
    #pragma unroll
    for (int i = 0; i < K; ++i) v[i] += __shfl_xor(v[i], off, 64);
  __syncthreads();
  if ((t & 63) == 0)
    #pragma unroll
    for (int i = 0; i < K; ++i) red[t >> 6][i] = v[i];
  __syncthreads();
  #pragma unroll
  for (int i = 0; i < K; ++i) v[i] = red[0][i] + red[1][i] + red[2][i] + red[3][i];
}

// ---------------- kernel 1: wave-per-row normalize -> fp8 e4m3 reps --------
__global__ __launch_bounds__(256) void normalize_kernel(
    const float* __restrict__ ei_, const float* __restrict__ ej_,
    const float* __restrict__ ek_,
    unsigned char* __restrict__ rep8, float* __restrict__ diagexp,
    float* __restrict__ pos_ij, float* __restrict__ exp_ik)
{
  const int t = threadIdx.x;
  const int l = t & 63;
  const int n = blockIdx.x * 4 + (t >> 6);
  const long base = (long)n * D + l * 8;

  float ai[8], aj[8], ak[8];
  #pragma unroll
  for (int h = 0; h < 2; ++h) {
    const float4 vi = *reinterpret_cast<const float4*>(ei_ + base + h * 4);
    const float4 vj = *reinterpret_cast<const float4*>(ej_ + base + h * 4);
    const float4 vk = *reinterpret_cast<const float4*>(ek_ + base + h * 4);
    ai[h*4+0]=vi.x; ai[h*4+1]=vi.y; ai[h*4+2]=vi.z; ai[h*4+3]=vi.w;
    aj[h*4+0]=vj.x; aj[h*4+1]=vj.y; aj[h*4+2]=vj.z; aj[h*4+3]=vj.w;
    ak[h*4+0]=vk.x; ak[h*4+1]=vk.y; ak[h*4+2]=vk.z; ak[h*4+3]=vk.w;
  }

  float v[5] = {0.f, 0.f, 0.f, 0.f, 0.f};
  #pragma unroll
  for (int j = 0; j < 8; ++j) {
    v[0] += ai[j] * ai[j];
    v[1] += aj[j] * aj[j];
    v[2] += ak[j] * ak[j];
    v[3] += ai[j] * aj[j];
    v[4] += ak[j] * ai[j];
  }
  #pragma unroll
  for (int off = 32; off; off >>= 1)
    #pragma unroll
    for (int i = 0; i < 5; ++i) v[i] += __shfl_xor(v[i], off, 64);

  const float ni = fmaxf(sqrtf(v[0]), 1e-12f);
  const float nj = fmaxf(sqrtf(v[1]), 1e-12f);
  const float nk = fmaxf(sqrtf(v[2]), 1e-12f);
  const float invi = 1.0f / ni, invj = 1.0f / nj;

  float zi[8], zj[8];
  #pragma unroll
  for (int j = 0; j < 8; ++j) { zi[j] = ai[j] * invi; zj[j] = aj[j] * invj; }
  int wi0 = __builtin_amdgcn_cvt_pk_fp8_f32(zi[0], zi[1], 0, false);
  wi0     = __builtin_amdgcn_cvt_pk_fp8_f32(zi[2], zi[3], wi0, true);
  int wi1 = __builtin_amdgcn_cvt_pk_fp8_f32(zi[4], zi[5], 0, false);
  wi1     = __builtin_amdgcn_cvt_pk_fp8_f32(zi[6], zi[7], wi1, true);
  int wj0 = __builtin_amdgcn_cvt_pk_fp8_f32(zj[0], zj[1], 0, false);
  wj0     = __builtin_amdgcn_cvt_pk_fp8_f32(zj[2], zj[3], wj0, true);
  int wj1 = __builtin_amdgcn_cvt_pk_fp8_f32(zj[4], zj[5], 0, false);
  wj1     = __builtin_amdgcn_cvt_pk_fp8_f32(zj[6], zj[7], wj1, true);
  int2 pi; pi.x = wi0; pi.y = wi1;
  int2 pj; pj.x = wj0; pj.y = wj1;
  *reinterpret_cast<int2*>(rep8 + base) = pi;
  *reinterpret_cast<int2*>(rep8 + (long)N_ROWS * D + base) = pj;

  // diag = sum of squares of the DEQUANTIZED values (matches MFMA diagonal)
  float q[2] = {0.f, 0.f};
  #pragma unroll
  for (int h = 0; h < 2; ++h) {
    const int wi = h ? wi1 : wi0, wj = h ? wj1 : wj0;
    const f32x2 d0 = __builtin_amdgcn_cvt_pk_f32_fp8(wi, false);
    const f32x2 d1 = __builtin_amdgcn_cvt_pk_f32_fp8(wi, true);
    const f32x2 e0 = __builtin_amdgcn_cvt_pk_f32_fp8(wj, false);
    const f32x2 e1 = __builtin_amdgcn_cvt_pk_f32_fp8(wj, true);
    q[0] += d0.x*d0.x + d0.y*d0.y + d1.x*d1.x + d1.y*d1.y;
    q[1] += e0.x*e0.x + e0.y*e0.y + e1.x*e1.x + e1.y*e1.y;
  }
  #pragma unroll
  for (int off = 32; off; off >>= 1)
    #pragma unroll
    for (int i = 0; i < 2; ++i) q[i] += __shfl_xor(q[i], off, 64);

  if (l == 0) {
    diagexp[n]          = __expf(INV_T * q[0]);
    diagexp[N_ROWS + n] = __expf(INV_T * q[1]);
    pos_ij[n] = v[3] / (ni * nj);
    exp_ik[n] = __expf(INV_T * v[4] / (nk * ni));
  }
}

// ---------------- kernel 2: reduce the two scalars --------------------------
__global__ __launch_bounds__(256) void scalar_kernel(
    const float* __restrict__ pos_ij, const float* __restrict__ exp_ik,
    float* __restrict__ scalars)
{
  const int t = threadIdx.x;
  float v[2] = {0.f, 0.f};
  for (int i = t; i < N_ROWS; i += 256) { v[0] += pos_ij[i]; v[1] += exp_ik[i]; }
  block_reduce_bcast<2>(v);
  if (t == 0) { scalars[0] = v[0]; scalars[1] = v[1]; }
}

// ---------------- kernel 3: 128^2 fp8, NO LDS, NO barriers -----------------
// Each lane loads its MFMA fragments DIRECTLY global->reg (dwordx4, const
// imm offsets kt*128+h*16 <= 416). rep8 = 4MB = one XCD's L2; per-block
// K-tile working set = 32KB = L1. No syncthreads in the K-loop at all:
// waves fully decoupled, latency hidden by TLP. Distinct L2 traffic
// 2080 x 128KB = 266MB (~8us floor); duplicates across waves hit L1.
// __launch_bounds__(256,2): unified budget 256/wave (acc 64 AGPR + ~130 V).
__global__ __launch_bounds__(256, 2) void gemm_expsum_kernel(
    const unsigned char* __restrict__ rep8, float* __restrict__ S_partial)
{
  __shared__ float rowbuf[2][TILE];
  __shared__ float colbuf[2][TILE];

  const int t = threadIdx.x;
  const int l = t & 63;
  const int w = t >> 6;          // wave 0..3
  const int wr = w >> 1, wc = w & 1;
  const int s4 = l >> 4;         // k-group 0..3

  // XCD-aware bijective swizzle (2080 = 8*260), then triangular decode I<=J
  const int wg = (blockIdx.x & 7) * 260 + (blockIdx.x >> 3);
  int k = wg, I = 0;
  while (k >= NJB - I) { k -= NJB - I; ++I; }
  const int J = I + k;
  const long rI = (long)I * TILE;
  const long cJ = (long)J * TILE;

  // per-lane fragment base pointers (include s4*32 k-byte base)
  const unsigned char* baseA[4];
  const unsigned char* baseB[4];
  #pragma unroll
  for (int mi = 0; mi < 4; ++mi)
    baseA[mi] = rep8 + (rI + wr * 64 + mi * 16 + (l & 15)) * (long)D + s4 * 32;
  #pragma unroll
  for (int ni = 0; ni < 4; ++ni)
    baseB[ni] = rep8 + (cJ + wc * 64 + ni * 16 + (l & 15)) * (long)D + s4 * 32;

  f32x4 acc[4][4];
  #pragma unroll
  for (int a = 0; a < 4; ++a)
    #pragma unroll
    for (int b = 0; b < 4; ++b) { f32x4 z = {0.f, 0.f, 0.f, 0.f}; acc[a][b] = z; }

  #pragma unroll
  for (int kt = 0; kt < NKT; ++kt) {
    i32x8 af[4], bf[4];
    #pragma unroll
    for (int mi = 0; mi < 4; ++mi) {
      const i32x4 lo = *reinterpret_cast<const i32x4*>(baseA[mi] + kt * 128);
      const i32x4 hi = *reinterpret_cast<const i32x4*>(baseA[mi] + kt * 128 + 16);
      af[mi] = __builtin_shufflevector(lo, hi, 0, 1, 2, 3, 4, 5, 6, 7);
    }
    #pragma unroll
    for (int ni = 0; ni < 4; ++ni) {
      const i32x4 lo = *reinterpret_cast<const i32x4*>(baseB[ni] + kt * 128);
      const i32x4 hi = *reinterpret_cast<const i32x4*>(baseB[ni] + kt * 128 + 16);
      bf[ni] = __builtin_shufflevector(lo, hi, 0, 1, 2, 3, 4, 5, 6, 7);
    }
    #pragma unroll
    for (int mi = 0; mi < 4; ++mi)
      #pragma unroll
      for (int ni = 0; ni < 4; ++ni)
        acc[mi][ni] = __builtin_amdgcn_mfma_scale_f32_16x16x128_f8f6f4(
            af[mi], bf[ni], acc[mi][ni], 0 /*A fmt fp8*/, 0 /*B fmt fp8*/,
            0, 0x7F7F7F7F, 0, 0x7F7F7F7F);
  }

  // epilogue: e = exp(5*sim); row-sums (rows of I) and col-sums (symmetry)
  // C/D layout shape-determined: col=l&15, row=(l>>4)*4+j
  float rsum[4][4], csum[4];
  #pragma unroll
  for (int mi = 0; mi < 4; ++mi)
    #pragma unroll
    for (int j = 0; j < 4; ++j) rsum[mi][j] = 0.f;
  #pragma unroll
  for (int ni = 0; ni < 4; ++ni) csum[ni] = 0.f;

  #pragma unroll
  for (int mi = 0; mi < 4; ++mi)
    #pragma unroll
    for (int ni = 0; ni < 4; ++ni)
      #pragma unroll
      for (int j = 0; j < 4; ++j) {
        const float e = __expf(INV_T * acc[mi][ni][j]);
        rsum[mi][j] += e;
        csum[ni]    += e;
      }

  #pragma unroll
  for (int mi = 0; mi < 4; ++mi) {
    #pragma unroll
    for (int off = 1; off < 16; off <<= 1)
      #pragma unroll
      for (int j = 0; j < 4; ++j) rsum[mi][j] += __shfl_xor(rsum[mi][j], off, 64);
    if ((l & 15) == 0) {
      const int rloc = wr * 64 + mi * 16 + s4 * 4;
      #pragma unroll
      for (int j = 0; j < 4; ++j) rowbuf[wc][rloc + j] = rsum[mi][j];
    }
  }
  #pragma unroll
  for (int off = 16; off < 64; off <<= 1)
    #pragma unroll
    for (int ni = 0; ni < 4; ++ni) csum[ni] += __shfl_xor(csum[ni], off, 64);
  if (l < 16) {
    #pragma unroll
    for (int ni = 0; ni < 4; ++ni)
      colbuf[wr][wc * 64 + ni * 16 + l] = csum[ni];
  }
  __syncthreads();

  if (t < TILE) {
    S_partial[(long)J * TWO_N + rI + t] = rowbuf[0][t] + rowbuf[1][t];
  } else if (I != J) {
    const int c = t - TILE;
    S_partial[(long)I * TWO_N + cJ + c] = colbuf[0][c] + colbuf[1][c];
  }
}

// ---------------- kernel 4: per-row log(denominator), block partials -------
__global__ __launch_bounds__(256) void rowlog_kernel(
    const float* __restrict__ S_partial, const float* __restrict__ diagexp,
    const float* __restrict__ scalars, float* __restrict__ blockpart)
{
  const int t = threadIdx.x;
  const int r = blockIdx.x * 256 + t;
  float s = 0.f;
  #pragma unroll 8
  for (int Jb = 0; Jb < NJB; ++Jb) s += S_partial[(long)Jb * TWO_N + r];
  const float denom_fu = 2.0f * scalars[1];
  float v[1];
  v[0] = logf(s - diagexp[r] + denom_fu);
  block_reduce_bcast<1>(v);
  if (t == 0) blockpart[blockIdx.x] = v[0];
}

// ---------------- kernel 5: final scalar -----------------------------------
__global__ void final_kernel(const float* __restrict__ blockpart,
                             const float* __restrict__ scalars,
                             float* __restrict__ out)
{
  const int t = threadIdx.x;   // 64 threads
  float s = (t < TWO_N / 256) ? blockpart[t] : 0.f;
  #pragma unroll
  for (int off = 32; off; off >>= 1) s += __shfl_xor(s, off, 64);
  if (t == 0) out[0] = (s - 10.0f * scalars[0]) / (float)TWO_N;
}

extern "C" void kernel_launch(void* const* d_in, const int* in_sizes, int n_in,
                              void* d_out, int out_size, void* d_ws, size_t ws_size,
                              hipStream_t stream)
{
  const float* ei = (const float*)d_in[0];
  const float* ej = (const float*)d_in[1];
  const float* ek = (const float*)d_in[2];
  float* out = (float*)d_out;

  char* ws = (char*)d_ws;
  unsigned char* rep8 = (unsigned char*)ws;                            // 4 MB
  float* S_partial = (float*)(ws + 4u * 1024 * 1024);                  // 2 MB
  float* diagexp   = (float*)(ws + 6u * 1024 * 1024);                  // 32 KB
  float* pos_ij    = (float*)(ws + 6u * 1024 * 1024 + 32 * 1024);      // 16 KB
  float* exp_ik    = (float*)(ws + 6u * 1024 * 1024 + 48 * 1024);      // 16 KB
  float* scalars   = (float*)(ws + 6u * 1024 * 1024 + 64 * 1024);      // 8 B
  float* blockpart = (float*)(ws + 6u * 1024 * 1024 + 64 * 1024 + 256); // 128 B

  normalize_kernel<<<N_ROWS / 4, 256, 0, stream>>>(ei, ej, ek, rep8, diagexp,
                                                   pos_ij, exp_ik);
  scalar_kernel<<<1, 256, 0, stream>>>(pos_ij, exp_ik, scalars);
  gemm_expsum_kernel<<<NPAIRS, 256, 0, stream>>>(rep8, S_partial);
  rowlog_kernel<<<TWO_N / 256, 256, 0, stream>>>(S_partial, diagexp, scalars,
                                                 blockpart);
  final_kernel<<<1, 64, 0, stream>>>(blockpart, scalars, out);
}

// Round 19
// 46.251 us; speedup vs baseline: 2.6540x; 1.9659x over previous
//
#include <hip/hip_runtime.h>
#include <hip/hip_bf16.h>
#include <math.h>

#define N_ROWS 4096
#define D 512
#define TWO_N 8192
#define TILE 128
#define NKT 4                /* 512 / 128 K-tiles */
#define NJB 64               /* 8192 / 128 column blocks */
#define NPAIRS 2080          /* 64*65/2 upper-tri blocks */
#define INV_T_EFF 0.01953125f   /* 5/256: acc = 256*sim (z scaled by 16) */

typedef __attribute__((ext_vector_type(4))) int i32x4;
typedef __attribute__((ext_vector_type(8))) int i32x8;
typedef __attribute__((ext_vector_type(4))) float f32x4;
#define AS1 __attribute__((address_space(1)))
#define AS3 __attribute__((address_space(3)))

// ---------------- block reduction helper (broadcasts result) ----------------
template<int K>
__device__ inline void block_reduce_bcast(float (&v)[K]) {
  __shared__ float red[4][K];
  const int t = threadIdx.x;
  #pragma unroll
  for (int off = 32; off; off >>= 1)
    #pragma unroll
    for (int i = 0; i < K; ++i) v[i] += __shfl_xor(v[i], off, 64);
  __syncthreads();
  if ((t & 63) == 0)
    #pragma unroll
    for (int i = 0; i < K; ++i) red[t >> 6][i] = v[i];
  __syncthreads();
  #pragma unroll
  for (int i = 0; i < K; ++i) v[i] = red[0][i] + red[1][i] + red[2][i] + red[3][i];
}

// e2m1 RNE encode of v (|v|<=~6 expected); returns nibble, sets q = decoded
__device__ __forceinline__ int enc_e2m1(float v, float& q) {
  const float a = fabsf(v);
  int idx; float m;
  if (a < 1.75f)      { m = rintf(a * 2.f) * 0.5f; idx = (int)(m * 2.f); }
  else if (a < 3.5f)  { m = rintf(a);              idx = (int)m + 2; }
  else if (a < 5.f)   { m = 4.f;                   idx = 6; }
  else                { m = 6.f;                   idx = 7; }
  if (v < 0.f) { q = -m; return idx | 8; }
  q = m; return idx;
}

// ---------------- kernel 1: wave-per-row normalize -> fp4 e2m1 reps --------
// Stores 16*z quantized to fp4 (2 elems/byte, row = 256B). diagexp computed
// from DEQUANTIZED values so the MFMA diagonal subtraction is exact.
__global__ __launch_bounds__(256) void normalize_kernel(
    const float* __restrict__ ei_, const float* __restrict__ ej_,
    const float* __restrict__ ek_,
    unsigned char* __restrict__ rep4, float* __restrict__ diagexp,
    float* __restrict__ pos_ij, float* __restrict__ exp_ik)
{
  const int t = threadIdx.x;
  const int l = t & 63;
  const int n = blockIdx.x * 4 + (t >> 6);
  const long base = (long)n * D + l * 8;

  float ai[8], aj[8], ak[8];
  #pragma unroll
  for (int h = 0; h < 2; ++h) {
    const float4 vi = *reinterpret_cast<const float4*>(ei_ + base + h * 4);
    const float4 vj = *reinterpret_cast<const float4*>(ej_ + base + h * 4);
    const float4 vk = *reinterpret_cast<const float4*>(ek_ + base + h * 4);
    ai[h*4+0]=vi.x; ai[h*4+1]=vi.y; ai[h*4+2]=vi.z; ai[h*4+3]=vi.w;
    aj[h*4+0]=vj.x; aj[h*4+1]=vj.y; aj[h*4+2]=vj.z; aj[h*4+3]=vj.w;
    ak[h*4+0]=vk.x; ak[h*4+1]=vk.y; ak[h*4+2]=vk.z; ak[h*4+3]=vk.w;
  }

  float v[5] = {0.f, 0.f, 0.f, 0.f, 0.f};
  #pragma unroll
  for (int j = 0; j < 8; ++j) {
    v[0] += ai[j] * ai[j];
    v[1] += aj[j] * aj[j];
    v[2] += ak[j] * ak[j];
    v[3] += ai[j] * aj[j];
    v[4] += ak[j] * ai[j];
  }
  #pragma unroll
  for (int off = 32; off; off >>= 1)
    #pragma unroll
    for (int i = 0; i < 5; ++i) v[i] += __shfl_xor(v[i], off, 64);

  const float ni = fmaxf(sqrtf(v[0]), 1e-12f);
  const float nj = fmaxf(sqrtf(v[1]), 1e-12f);
  const float nk = fmaxf(sqrtf(v[2]), 1e-12f);
  const float invi = 16.0f / ni, invj = 16.0f / nj;   // 16x scale for fp4

  unsigned wi = 0, wj = 0;
  float q[2] = {0.f, 0.f};
  #pragma unroll
  for (int j = 0; j < 8; ++j) {
    float qi, qj;
    wi |= (unsigned)enc_e2m1(ai[j] * invi, qi) << (4 * j);
    wj |= (unsigned)enc_e2m1(aj[j] * invj, qj) << (4 * j);
    q[0] += qi * qi;
    q[1] += qj * qj;
  }
  *reinterpret_cast<unsigned*>(rep4 + (long)n * 256 + l * 4) = wi;
  *reinterpret_cast<unsigned*>(rep4 + (long)(N_ROWS + n) * 256 + l * 4) = wj;

  #pragma unroll
  for (int off = 32; off; off >>= 1)
    #pragma unroll
    for (int i = 0; i < 2; ++i) q[i] += __shfl_xor(q[i], off, 64);

  if (l == 0) {
    diagexp[n]          = __expf(INV_T_EFF * q[0]);   // exp(5*||zq||^2)
    diagexp[N_ROWS + n] = __expf(INV_T_EFF * q[1]);
    pos_ij[n] = v[3] / (ni * nj);                     // exact fp32
    exp_ik[n] = __expf(5.0f * v[4] / (nk * ni));
  }
}

// ---------------- kernel 2: reduce the two scalars --------------------------
__global__ __launch_bounds__(256) void scalar_kernel(
    const float* __restrict__ pos_ij, const float* __restrict__ exp_ik,
    float* __restrict__ scalars)
{
  const int t = threadIdx.x;
  float v[2] = {0.f, 0.f};
  for (int i = t; i < N_ROWS; i += 256) { v[0] += pos_ij[i]; v[1] += exp_ik[i]; }
  block_reduce_bcast<2>(v);
  if (t == 0) { scalars[0] = v[0]; scalars[1] = v[1]; }
}

// ---------------- kernel 3: 128^2 MX-fp4 K=128 GEMM + exp + sums -----------
// R12's proven structure, FMT=4 (fp4): same instruction count, HW runs fp4
// 1.55x faster (m25 vs m21) and staged bytes HALVE (16KB/K-tile; rep4=2MB).
// A and B staged identically -> any k-permutation in operand layout cancels.
// Row = 64B = 4 slots of 16B; swizzle slot^((row>>1)&3) (2 lanes/bank=free);
// inverse swizzle on global source. Unit e8m0 scales (0x7F = 2^0).
__device__ __forceinline__ void stage4(
    const unsigned char* __restrict__ rep4, char* region,
    long R0, int kt, int t)
{
  #pragma unroll
  for (int s = 0; s < 2; ++s) {
    const int cc = s * 256 + t;          // chunk 0..511
    const int row = cc >> 2, slot = cc & 3;
    const int sg = slot ^ ((row >> 1) & 3);   // inverse-swizzled source slot
    const unsigned char* g = rep4 + (R0 + row) * 256 + kt * 64 + sg * 16;
    __builtin_amdgcn_global_load_lds((const AS1 void*)g,
        (AS3 void*)(region + cc * 16), 16, 0, 0);
  }
}

__global__ __launch_bounds__(256, 2) void gemm_expsum_kernel(
    const unsigned char* __restrict__ rep4, float* __restrict__ S_partial)
{
  __shared__ __align__(16) char smem[16384];   // A 8K | B 8K

  const int t = threadIdx.x;
  const int l = t & 63;
  const int w = t >> 6;          // wave 0..3
  const int wr = w >> 1, wc = w & 1;
  const int s4 = l >> 4;         // k-group 0..3

  // XCD-aware bijective swizzle (2080 = 8*260), then triangular decode I<=J
  const int wg = (blockIdx.x & 7) * 260 + (blockIdx.x >> 3);
  int k = wg, I = 0;
  while (k >= NJB - I) { k -= NJB - I; ++I; }
  const int J = I + k;
  const long rI = (long)I * TILE;
  const long cJ = (long)J * TILE;

  // fragment byte offsets: row*64 + swizzled 16B slot ((row>>1)&3 == (l>>1)&3)
  const int swz16 = ((s4 ^ ((l >> 1) & 3)) << 4);
  int a_off[4], b_off[4];
  #pragma unroll
  for (int mi = 0; mi < 4; ++mi)
    a_off[mi] = (wr * 64 + mi * 16 + (l & 15)) * 64 + swz16;
  #pragma unroll
  for (int ni = 0; ni < 4; ++ni)
    b_off[ni] = 8192 + (wc * 64 + ni * 16 + (l & 15)) * 64 + swz16;

  f32x4 acc[4][4];
  #pragma unroll
  for (int a = 0; a < 4; ++a)
    #pragma unroll
    for (int b = 0; b < 4; ++b) { f32x4 z = {0.f, 0.f, 0.f, 0.f}; acc[a][b] = z; }

  const i32x4 zero4 = {0, 0, 0, 0};

  for (int kt = 0; kt < NKT; ++kt) {
    if (kt) __syncthreads();             // everyone done reading prev tile
    stage4(rep4, smem, rI, kt, t);
    stage4(rep4, smem + 8192, cJ, kt, t);
    __syncthreads();                     // drains vmcnt(0): tile landed

    i32x8 bf[4];
    #pragma unroll
    for (int ni = 0; ni < 4; ++ni) {
      const i32x4 lo = *reinterpret_cast<const i32x4*>(smem + b_off[ni]);
      bf[ni] = __builtin_shufflevector(lo, zero4, 0, 1, 2, 3, 4, 5, 6, 7);
    }
    __builtin_amdgcn_s_setprio(1);
    #pragma unroll
    for (int mi = 0; mi < 4; ++mi) {
      const i32x4 lo = *reinterpret_cast<const i32x4*>(smem + a_off[mi]);
      const i32x8 af = __builtin_shufflevector(lo, zero4, 0, 1, 2, 3, 4, 5, 6, 7);
      #pragma unroll
      for (int ni = 0; ni < 4; ++ni)
        acc[mi][ni] = __builtin_amdgcn_mfma_scale_f32_16x16x128_f8f6f4(
            af, bf[ni], acc[mi][ni], 4 /*A fmt fp4*/, 4 /*B fmt fp4*/,
            0, 0x7F7F7F7F, 0, 0x7F7F7F7F);
    }
    __builtin_amdgcn_s_setprio(0);
  }
  __syncthreads();                       // all ds_reads retired: smem reusable
  float* rowbuf = (float*)smem;          // [2][128]
  float* colbuf = (float*)(smem + 1024); // [2][128]

  // epilogue: e = exp((5/256)*acc); row-sums + col-sums (symmetry)
  // C/D layout shape-determined: col=l&15, row=(l>>4)*4+j
  float rsum[4][4], csum[4];
  #pragma unroll
  for (int mi = 0; mi < 4; ++mi)
    #pragma unroll
    for (int j = 0; j < 4; ++j) rsum[mi][j] = 0.f;
  #pragma unroll
  for (int ni = 0; ni < 4; ++ni) csum[ni] = 0.f;

  #pragma unroll
  for (int mi = 0; mi < 4; ++mi)
    #pragma unroll
    for (int ni = 0; ni < 4; ++ni)
      #pragma unroll
      for (int j = 0; j < 4; ++j) {
        const float e = __expf(INV_T_EFF * acc[mi][ni][j]);
        rsum[mi][j] += e;
        csum[ni]    += e;
      }

  #pragma unroll
  for (int mi = 0; mi < 4; ++mi) {
    #pragma unroll
    for (int off = 1; off < 16; off <<= 1)
      #pragma unroll
      for (int j = 0; j < 4; ++j) rsum[mi][j] += __shfl_xor(rsum[mi][j], off, 64);
    if ((l & 15) == 0) {
      const int rloc = wr * 64 + mi * 16 + s4 * 4;
      #pragma unroll
      for (int j = 0; j < 4; ++j) rowbuf[wc * TILE + rloc + j] = rsum[mi][j];
    }
  }
  #pragma unroll
  for (int off = 16; off < 64; off <<= 1)
    #pragma unroll
    for (int ni = 0; ni < 4; ++ni) csum[ni] += __shfl_xor(csum[ni], off, 64);
  if (l < 16) {
    #pragma unroll
    for (int ni = 0; ni < 4; ++ni)
      colbuf[wr * TILE + wc * 64 + ni * 16 + l] = csum[ni];
  }
  __syncthreads();

  if (t < TILE) {
    S_partial[(long)J * TWO_N + rI + t] = rowbuf[t] + rowbuf[TILE + t];
  } else if (I != J) {
    const int c = t - TILE;
    S_partial[(long)I * TWO_N + cJ + c] = colbuf[c] + colbuf[TILE + c];
  }
}

// ---------------- kernel 4: per-row log(denominator), block partials -------
__global__ __launch_bounds__(256) void rowlog_kernel(
    const float* __restrict__ S_partial, const float* __restrict__ diagexp,
    const float* __restrict__ scalars, float* __restrict__ blockpart)
{
  const int t = threadIdx.x;
  const int r = blockIdx.x * 256 + t;
  float s = 0.f;
  #pragma unroll 8
  for (int Jb = 0; Jb < NJB; ++Jb) s += S_partial[(long)Jb * TWO_N + r];
  const float denom_fu = 2.0f * scalars[1];
  float v[1];
  v[0] = logf(s - diagexp[r] + denom_fu);
  block_reduce_bcast<1>(v);
  if (t == 0) blockpart[blockIdx.x] = v[0];
}

// ---------------- kernel 5: final scalar -----------------------------------
__global__ void final_kernel(const float* __restrict__ blockpart,
                             const float* __restrict__ scalars,
                             float* __restrict__ out)
{
  const int t = threadIdx.x;   // 64 threads
  float s = (t < TWO_N / 256) ? blockpart[t] : 0.f;
  #pragma unroll
  for (int off = 32; off; off >>= 1) s += __shfl_xor(s, off, 64);
  if (t == 0) out[0] = (s - 10.0f * scalars[0]) / (float)TWO_N;
}

extern "C" void kernel_launch(void* const* d_in, const int* in_sizes, int n_in,
                              void* d_out, int out_size, void* d_ws, size_t ws_size,
                              hipStream_t stream)
{
  const float* ei = (const float*)d_in[0];
  const float* ej = (const float*)d_in[1];
  const float* ek = (const float*)d_in[2];
  float* out = (float*)d_out;

  char* ws = (char*)d_ws;
  unsigned char* rep4 = (unsigned char*)ws;                            // 2 MB
  float* S_partial = (float*)(ws + 2u * 1024 * 1024);                  // 2 MB
  float* diagexp   = (float*)(ws + 4u * 1024 * 1024);                  // 32 KB
  float* pos_ij    = (float*)(ws + 4u * 1024 * 1024 + 32 * 1024);      // 16 KB
  float* exp_ik    = (float*)(ws + 4u * 1024 * 1024 + 48 * 1024);      // 16 KB
  float* scalars   = (float*)(ws + 4u * 1024 * 1024 + 64 * 1024);      // 8 B
  float* blockpart = (float*)(ws + 4u * 1024 * 1024 + 64 * 1024 + 256); // 128 B

  normalize_kernel<<<N_ROWS / 4, 256, 0, stream>>>(ei, ej, ek, rep4, diagexp,
                                                   pos_ij, exp_ik);
  scalar_kernel<<<1, 256, 0, stream>>>(pos_ij, exp_ik, scalars);
  gemm_expsum_kernel<<<NPAIRS, 256, 0, stream>>>(rep4, S_partial);
  rowlog_kernel<<<TWO_N / 256, 256, 0, stream>>>(S_partial, diagexp, scalars,
                                                 blockpart);
  final_kernel<<<1, 64, 0, stream>>>(blockpart, scalars, out);
}